// Round 6
// baseline (587.858 us; speedup 1.0000x reference)
//
#include <hip/hip_runtime.h>

// MoE: B=4,S=2048 -> T=8192 tokens, D=1024, H=2048, O=1024, E=8, K=2
#define T_TOKENS 8192
#define D_DIM 1024
#define H_DIM 2048
#define O_DIM 1024
#define E_NUM 8
#define NPAIR 16384   // T_TOKENS * 2
#define GY_MAX 136    // >= max possible sum ceil(ne/128) = 135

typedef unsigned short u16;
typedef __bf16 bf16x8 __attribute__((ext_vector_type(8)));
typedef float f32x4 __attribute__((ext_vector_type(4)));

__device__ inline u16 f2bf(float f) {
  union { float f; unsigned u; } v; v.f = f;
  unsigned r = v.u + 0x7FFFu + ((v.u >> 16) & 1u);   // RNE
  return (u16)(r >> 16);
}

// async 16B global -> LDS (deposits at wave-uniform base + lane*16)
__device__ __forceinline__ void gload16(const u16* g, u16* l) {
  __builtin_amdgcn_global_load_lds((const __attribute__((address_space(1))) void*)g,
                                   (__attribute__((address_space(3))) void*)l, 16, 0, 0);
}

// ---------------- prep: transpose+cast weights: [E,R,C] f32 -> [E,C,R] bf16 ----
// 64x64 tiles, block (64,4): reads 256B/wave-row, transposed writes 128B/wave-row
// (2x the 32x32 version's 64B segments).
__global__ void transpose_cvt_kernel(const float* __restrict__ w, u16* __restrict__ wt,
                                     int R, int C) {
  __shared__ float tile[64][65];
  int e = blockIdx.z;
  int c0 = blockIdx.x * 64, r0 = blockIdx.y * 64;
  const float* wp = w + (size_t)e * R * C;
  u16* wtp = wt + (size_t)e * R * C;
  int tx = threadIdx.x, ty = threadIdx.y;  // (64,4)
  #pragma unroll
  for (int j = 0; j < 64; j += 4)
    tile[ty + j][tx] = wp[(size_t)(r0 + ty + j) * C + c0 + tx];
  __syncthreads();
  #pragma unroll
  for (int j = 0; j < 64; j += 4)
    wtp[(size_t)(c0 + ty + j) * R + r0 + tx] = f2bf(tile[tx][ty + j]);
}

// ---------------- gating + x->bf16 cast fused (NO atomics) ----------------
__global__ void gate_kernel(const float* __restrict__ x, const float* __restrict__ gw,
                            const float* __restrict__ gb, int* __restrict__ topk_idx,
                            float* __restrict__ topk_val, u16* __restrict__ xb) {
  int t = blockIdx.x * 4 + (threadIdx.x >> 6);   // one wave per token
  int lane = threadIdx.x & 63;
  const float4* xr4 = (const float4*)(x + (size_t)t * D_DIM);
  const float4* gw4 = (const float4*)gw;
  u16* xbr = xb + (size_t)t * D_DIM;
  float acc[E_NUM];
  #pragma unroll
  for (int e = 0; e < E_NUM; e++) acc[e] = 0.f;
  #pragma unroll
  for (int it = 0; it < D_DIM / 256; ++it) {
    float4 xv = xr4[it * 64 + lane];
    ushort4 o;
    o.x = f2bf(xv.x); o.y = f2bf(xv.y); o.z = f2bf(xv.z); o.w = f2bf(xv.w);
    *(ushort4*)(xbr + (it * 64 + lane) * 4) = o;
    #pragma unroll
    for (int e = 0; e < E_NUM; e++) {
      float4 wv = gw4[e * (D_DIM / 4) + it * 64 + lane];
      acc[e] += xv.x * wv.x + xv.y * wv.y + xv.z * wv.z + xv.w * wv.w;
    }
  }
  #pragma unroll
  for (int e = 0; e < E_NUM; e++) {
    #pragma unroll
    for (int o = 32; o > 0; o >>= 1) acc[e] += __shfl_down(acc[e], o);
  }
  if (lane == 0) {
    float l[E_NUM], mx = -1e30f;
    #pragma unroll
    for (int e = 0; e < E_NUM; e++) { l[e] = acc[e] + gb[e]; mx = fmaxf(mx, l[e]); }
    float p[E_NUM], s = 0.f;
    #pragma unroll
    for (int e = 0; e < E_NUM; e++) { p[e] = expf(l[e] - mx); s += p[e]; }
    float inv = 1.f / s;
    int i1 = 0;
    #pragma unroll
    for (int e = 1; e < E_NUM; e++) if (p[e] > p[i1]) i1 = e;   // strict >: lowest idx on tie
    int i2 = (i1 == 0) ? 1 : 0;
    #pragma unroll
    for (int e = 0; e < E_NUM; e++) if (e != i1 && e != i2 && p[e] > p[i2]) i2 = e;
    topk_idx[t * 2] = i1;     topk_idx[t * 2 + 1] = i2;
    topk_val[t * 2] = p[i1] * inv; topk_val[t * 2 + 1] = p[i2] * inv;
  }
}

// ---------------- histogram + scan + tile table: 1 block ----------------
__global__ void histscan_kernel(const int* __restrict__ topk_idx,
                                int* __restrict__ counts, int* __restrict__ eoff,
                                int* __restrict__ nblk, int* __restrict__ tbl_e,
                                int* __restrict__ tbl_m0) {
  __shared__ int wh[4][E_NUM];
  int tid = threadIdx.x;           // 256 threads
  int lane = tid & 63, wave = tid >> 6;
  int myc = 0;                     // lane e (<8) accumulates count of expert e
  for (int i = tid; i < NPAIR; i += 256) {
    int e = topk_idx[i];
    #pragma unroll
    for (int ee = 0; ee < E_NUM; ee++) {
      unsigned long long m = __ballot(e == ee);
      if (lane == ee) myc += __popcll(m);
    }
  }
  if (lane < E_NUM) wh[wave][lane] = myc;
  __syncthreads();
  if (tid == 0) {
    int s = 0, cl[E_NUM];
    for (int e = 0; e < E_NUM; e++) {
      int c = wh[0][e] + wh[1][e] + wh[2][e] + wh[3][e];
      counts[e] = c;
      cl[e] = c;
      eoff[e] = s;
      s += c;
    }
    eoff[E_NUM] = s;
    // flattened M-tile table shared by gemm1/gemm2 (BM=128)
    int nb = 0;
    for (int e = 0; e < E_NUM; e++)
      for (int m0 = 0; m0 < cl[e]; m0 += 128) { tbl_e[nb] = e; tbl_m0[nb] = m0; nb++; }
    nblk[0] = nb;   // <= 135
  }
}

// ---------------- scatter: per-block LDS agg + padded global cursors --------
// also writes inv_pos[t*2 + slot] = pair position of token t's slot-th expert
__global__ void scatter_kernel(const int* __restrict__ topk_idx, const float* __restrict__ topk_val,
                               const int* __restrict__ eoff, int* __restrict__ cursor_pad,
                               int* __restrict__ pair_token, int* __restrict__ inv_pos) {
  __shared__ int lhist[E_NUM];
  __shared__ int lbase[E_NUM];
  int tid = threadIdx.x;
  int t = blockIdx.x * 256 + tid;
  if (tid < E_NUM) lhist[tid] = 0;
  __syncthreads();
  int e0 = topk_idx[t * 2], e1 = topk_idx[t * 2 + 1];
  int r0 = atomicAdd(&lhist[e0], 1);
  int r1 = atomicAdd(&lhist[e1], 1);
  __syncthreads();
  if (tid < E_NUM) lbase[tid] = eoff[tid] + atomicAdd(&cursor_pad[tid * 32], lhist[tid]);
  __syncthreads();
  int p0 = lbase[e0] + r0;
  int p1 = lbase[e1] + r1;
  pair_token[p0] = t;
  pair_token[p1] = t;
  inv_pos[t * 2] = p0;
  inv_pos[t * 2 + 1] = p1;
}

// ---------------- combine: out[t] = g0*obuf[p0] + g1*obuf[p1] (no atomics) ----
__global__ void combine_kernel(const float* __restrict__ obuf, const int* __restrict__ inv_pos,
                               const float* __restrict__ topk_val, float* __restrict__ out) {
  int t = blockIdx.x;
  int tid = threadIdx.x;            // 256 threads, float4 each -> 1024 floats
  int p0 = inv_pos[t * 2], p1 = inv_pos[t * 2 + 1];
  float g0 = topk_val[t * 2], g1 = topk_val[t * 2 + 1];
  const float4* a4 = (const float4*)(obuf + (size_t)p0 * O_DIM);
  const float4* b4 = (const float4*)(obuf + (size_t)p1 * O_DIM);
  float4 a = a4[tid], b = b4[tid];
  float4 r;
  r.x = g0 * a.x + g1 * b.x;
  r.y = g0 * a.y + g1 * b.y;
  r.z = g0 * a.z + g1 * b.z;
  r.w = g0 * a.w + g1 * b.w;
  ((float4*)(out + (size_t)t * O_DIM))[tid] = r;
}

// ===================== GEMM core (m97-verified structure) =====================
// BK=64 SINGLE-buffer, 2 __syncthreads per 64-K tile, 32 MFMA per tile.
// 32KB LDS -> 4 blocks/CU via __launch_bounds__(256,4); the barrier drain is
// hidden by cross-block overlap (m97/m114 mechanism), which measured 874-912 TF
// on this exact tile geometry — vs 625 TF for the BK=32 triple-buffer variant
// (2x the barrier frequency). LDS layout: row stride 64 u16 (128B); 16B chunk
// g of row r at slot (g ^ (r&7)): linear global_load_lds deposit with
// pre-inverse-swizzled source + conflict-free ds_read_b128 (0 conflicts,
// verified rounds 0-5).

#define GEMM_DECLS                                                             \
  __shared__ __align__(16) u16 As[128 * 64];                                   \
  __shared__ __align__(16) u16 Bs[128 * 64];                                   \
  const int tid = threadIdx.x;                                                 \
  const int wid = tid >> 6;                                                    \
  const int lane = tid & 63;                                                   \
  const int strow8 = lane >> 3;                                                \
  const int slot = lane & 7;                                                   \
  const int wm = (wid & 1) * 64;                                               \
  const int wn = (wid >> 1) * 64;                                              \
  const int lrow = lane & 15;                                                  \
  const int quad = lane >> 4;                                                  \
  const int pg0 = quad ^ (lrow & 7);                                           \
  const int pg1 = (quad + 4) ^ (lrow & 7);                                     \
  f32x4 acc[4][4] = {};                                                        \
  auto KTILE = [&](int k0) {                                                   \
    _Pragma("unroll")                                                          \
    for (int j = 0; j < 4; j++) {                                              \
      gload16(aptr[j] + k0, As + wid * 2048 + j * 512);                        \
      gload16(bptr[j] + k0, Bs + wid * 2048 + j * 512);                        \
    }                                                                          \
    __syncthreads();                                                           \
    {                                                                          \
      bf16x8 af[4], bfr[4];                                                    \
      _Pragma("unroll")                                                        \
      for (int i = 0; i < 4; i++) af[i] = *(const bf16x8*)&As[(wm + i * 16 + lrow) * 64 + pg0 * 8]; \
      _Pragma("unroll")                                                        \
      for (int j = 0; j < 4; j++) bfr[j] = *(const bf16x8*)&Bs[(wn + j * 16 + lrow) * 64 + pg0 * 8]; \
      _Pragma("unroll")                                                        \
      for (int i = 0; i < 4; i++)                                              \
        _Pragma("unroll")                                                      \
        for (int j = 0; j < 4; j++)                                            \
          acc[i][j] = __builtin_amdgcn_mfma_f32_16x16x32_bf16(af[i], bfr[j], acc[i][j], 0, 0, 0); \
    }                                                                          \
    {                                                                          \
      bf16x8 af[4], bfr[4];                                                    \
      _Pragma("unroll")                                                        \
      for (int i = 0; i < 4; i++) af[i] = *(const bf16x8*)&As[(wm + i * 16 + lrow) * 64 + pg1 * 8]; \
      _Pragma("unroll")                                                        \
      for (int j = 0; j < 4; j++) bfr[j] = *(const bf16x8*)&Bs[(wn + j * 16 + lrow) * 64 + pg1 * 8]; \
      _Pragma("unroll")                                                        \
      for (int i = 0; i < 4; i++)                                              \
        _Pragma("unroll")                                                      \
        for (int j = 0; j < 4; j++)                                            \
          acc[i][j] = __builtin_amdgcn_mfma_f32_16x16x32_bf16(af[i], bfr[j], acc[i][j], 0, 0, 0); \
    }                                                                          \
    __syncthreads();                                                           \
  }

// ---------------- GEMM1: h = relu(x[tok] @ w1[e] + b1[e]) -> hbuf bf16 ----------------
__global__ __launch_bounds__(256, 4) void gemm1_kernel(
    const u16* __restrict__ xb, const u16* __restrict__ w1t, const float* __restrict__ b1,
    const int* __restrict__ pair_token, const int* __restrict__ eoff,
    const int* __restrict__ ecnt, const int* __restrict__ nblk,
    const int* __restrict__ tbl_e, const int* __restrict__ tbl_m0,
    u16* __restrict__ hbuf) {
  // XCD-chunk swizzle over nwg = 16*GY_MAX = 2176 (chunk 272)
  int lin = blockIdx.y * 16 + blockIdx.x;
  int swz = (lin & 7) * (16 * GY_MAX / 8) + (lin >> 3);
  const int bx = swz & 15;
  const int yb = swz >> 4;
  if (yb >= nblk[0]) return;
  const int e = tbl_e[yb];
  const int m0t = tbl_m0[yb];
  const int ne = ecnt[e];
  const int off = eoff[e];
  const int n0 = bx * 128;

  // staging: wave wid covers rows [wid*32, wid*32+32), 4 issues of 8 rows
  const u16* aptr[4]; const u16* bptr[4];
  {
    const int wid_ = threadIdx.x >> 6, lane_ = threadIdx.x & 63;
    #pragma unroll
    for (int j = 0; j < 4; j++) {
      int r = wid_ * 32 + j * 8 + (lane_ >> 3);
      int gm = m0t + r;
      int tok = (gm < ne) ? pair_token[off + gm] : 0;
      int gl = (lane_ & 7) ^ (r & 7);          // logical chunk this lane fetches
      aptr[j] = xb + (size_t)tok * D_DIM + gl * 8;
      bptr[j] = w1t + ((size_t)e * H_DIM + (n0 + r)) * D_DIM + gl * 8;
    }
  }

  GEMM_DECLS;

  for (int k0 = 0; k0 < D_DIM; k0 += 64) KTILE(k0);

  // epilogue: +b1, relu, bf16 store. C/D: col=lane&15, row=quad*4+reg
  #pragma unroll
  for (int i = 0; i < 4; i++) {
    #pragma unroll
    for (int r = 0; r < 4; r++) {
      int m = wm + i * 16 + quad * 4 + r;
      int gm = m0t + m;
      if (gm >= ne) continue;
      size_t rowbase = (size_t)(off + gm) * H_DIM;
      #pragma unroll
      for (int j = 0; j < 4; j++) {
        int n = n0 + wn + j * 16 + lrow;
        float v = acc[i][j][r] + b1[e * H_DIM + n];
        v = v > 0.f ? v : 0.f;
        hbuf[rowbase + n] = f2bf(v);
      }
    }
  }
}

// ---------------- GEMM2: obuf[pair] = h[pair] @ w2[e] + b2[e] (plain stores) ----
__global__ __launch_bounds__(256, 4) void gemm2_kernel(
    const u16* __restrict__ hbuf, const u16* __restrict__ w2t, const float* __restrict__ b2,
    const int* __restrict__ eoff, const int* __restrict__ ecnt,
    const int* __restrict__ nblk, const int* __restrict__ tbl_e,
    const int* __restrict__ tbl_m0, float* __restrict__ obuf) {
  // XCD-chunk swizzle over nwg = 8*GY_MAX = 1088 (chunk 136)
  int lin = blockIdx.y * 8 + blockIdx.x;
  int swz = (lin & 7) * (8 * GY_MAX / 8) + (lin >> 3);
  const int bx = swz & 7;
  const int yb = swz >> 3;
  if (yb >= nblk[0]) return;
  const int e = tbl_e[yb];
  const int m0t = tbl_m0[yb];
  const int ne = ecnt[e];
  const int off = eoff[e];
  const int n0 = bx * 128;

  const u16* aptr[4]; const u16* bptr[4];
  {
    const int wid_ = threadIdx.x >> 6, lane_ = threadIdx.x & 63;
    #pragma unroll
    for (int j = 0; j < 4; j++) {
      int r = wid_ * 32 + j * 8 + (lane_ >> 3);
      int gl = (lane_ & 7) ^ (r & 7);
      // hbuf has 128 slack rows past NPAIR; out-of-range rows discarded in epilogue
      aptr[j] = hbuf + (size_t)(off + m0t + r) * H_DIM + gl * 8;
      bptr[j] = w2t + ((size_t)e * O_DIM + (n0 + r)) * H_DIM + gl * 8;
    }
  }

  GEMM_DECLS;

  for (int k0 = 0; k0 < H_DIM; k0 += 64) KTILE(k0);

  // epilogue: +b2, plain f32 store into private pair row (NO atomics;
  // gate weighting + token reduction happen in combine_kernel)
  #pragma unroll
  for (int i = 0; i < 4; i++) {
    #pragma unroll
    for (int r = 0; r < 4; r++) {
      int m = wm + i * 16 + quad * 4 + r;
      int gm = m0t + m;
      if (gm >= ne) continue;
      size_t rowbase = (size_t)(off + gm) * O_DIM;
      #pragma unroll
      for (int j = 0; j < 4; j++) {
        int n = n0 + wn + j * 16 + lrow;
        obuf[rowbase + n] = acc[i][j][r] + b2[e * O_DIM + n];
      }
    }
  }
}

extern "C" void kernel_launch(void* const* d_in, const int* in_sizes, int n_in,
                              void* d_out, int out_size, void* d_ws, size_t ws_size,
                              hipStream_t stream) {
  const float* x  = (const float*)d_in[0];
  const float* gw = (const float*)d_in[1];
  const float* gb = (const float*)d_in[2];
  const float* w1 = (const float*)d_in[3];
  const float* b1 = (const float*)d_in[4];
  const float* w2 = (const float*)d_in[5];
  const float* b2 = (const float*)d_in[6];
  float* out = (float*)d_out;

  char* ws = (char*)d_ws;
  size_t off = 0;
  auto take = [&](size_t bytes) -> char* {
    char* p = ws + off;
    off = (off + bytes + 255) & ~(size_t)255;
    return p;
  };
  int*   meta       = (int*)take(4096);  // cursor_pad[256] | counts[8] | eoff[9] | nblk | tbl_e[136] | tbl_m0[136]
  int*   cursor_pad = meta;
  int*   counts     = meta + 256;
  int*   eoff       = meta + 264;
  int*   nblk       = meta + 273;
  int*   tbl_e      = meta + 274;
  int*   tbl_m0     = meta + 410;
  int*   topk_idx   = (int*)take((size_t)T_TOKENS * 2 * 4);
  float* topk_val   = (float*)take((size_t)T_TOKENS * 2 * 4);
  int*   pair_token = (int*)take((size_t)(NPAIR + 256) * 4);
  int*   inv_pos    = (int*)take((size_t)T_TOKENS * 2 * 4);
  u16*   xb         = (u16*)take((size_t)T_TOKENS * D_DIM * 2);
  u16*   w1t        = (u16*)take((size_t)E_NUM * D_DIM * H_DIM * 2);
  u16*   w2t        = (u16*)take((size_t)E_NUM * H_DIM * O_DIM * 2);
  u16*   hbuf       = (u16*)take((size_t)(NPAIR + 128) * H_DIM * 2);
  float* obuf       = (float*)take((size_t)(NPAIR + 128) * O_DIM * 4);

  hipMemsetAsync(meta, 0, 4096, stream);

  transpose_cvt_kernel<<<dim3(H_DIM / 64, D_DIM / 64, E_NUM), dim3(64, 4), 0, stream>>>(w1, w1t, D_DIM, H_DIM);
  transpose_cvt_kernel<<<dim3(O_DIM / 64, H_DIM / 64, E_NUM), dim3(64, 4), 0, stream>>>(w2, w2t, H_DIM, O_DIM);
  gate_kernel<<<T_TOKENS / 4, 256, 0, stream>>>(x, gw, gb, topk_idx, topk_val, xb);
  histscan_kernel<<<1, 256, 0, stream>>>(topk_idx, counts, eoff, nblk, tbl_e, tbl_m0);
  scatter_kernel<<<T_TOKENS / 256, 256, 0, stream>>>(topk_idx, topk_val, eoff, cursor_pad, pair_token, inv_pos);
  gemm1_kernel<<<dim3(16, GY_MAX), 256, 0, stream>>>(xb, w1t, b1, pair_token, eoff, counts, nblk, tbl_e, tbl_m0, hbuf);
  gemm2_kernel<<<dim3(8, GY_MAX), 256, 0, stream>>>(hbuf, w2t, b2, eoff, counts, nblk, tbl_e, tbl_m0, obuf);
  combine_kernel<<<T_TOKENS, 256, 0, stream>>>(obuf, inv_pos, topk_val, out);
}

// Round 7
// 433.464 us; speedup vs baseline: 1.3562x; 1.3562x over previous
//
#include <hip/hip_runtime.h>

// MoE: B=4,S=2048 -> T=8192 tokens, D=1024, H=2048, O=1024, E=8, K=2
#define T_TOKENS 8192
#define D_DIM 1024
#define H_DIM 2048
#define O_DIM 1024
#define E_NUM 8
#define NPAIR 16384   // T_TOKENS * 2
#define GY_MAX 136    // >= max possible sum ceil(ne/128) = 135

typedef unsigned short u16;
typedef __bf16 bf16x8 __attribute__((ext_vector_type(8)));
typedef float f32x4 __attribute__((ext_vector_type(4)));

// counted waitcnt: loads stay in flight across barriers; literal immediate.
#define VMCNT(n) asm volatile("s_waitcnt vmcnt(" #n ")" ::: "memory")

__device__ __forceinline__ void barsync() {
  asm volatile("" ::: "memory");
  __builtin_amdgcn_s_barrier();
  __builtin_amdgcn_sched_barrier(0);
}

__device__ inline u16 f2bf(float f) {
  union { float f; unsigned u; } v; v.f = f;
  unsigned r = v.u + 0x7FFFu + ((v.u >> 16) & 1u);   // RNE
  return (u16)(r >> 16);
}

// async 16B global -> LDS (deposits at wave-uniform base + lane*16)
__device__ __forceinline__ void gload16(const u16* g, u16* l) {
  __builtin_amdgcn_global_load_lds((const __attribute__((address_space(1))) void*)g,
                                   (__attribute__((address_space(3))) void*)l, 16, 0, 0);
}

// ---------------- prep: BOTH weight transposes in ONE launch ----------------
// [E,R,C] f32 -> [E,C,R] bf16, 32x32 tiles (R5-verified body).
// bid < 16384: w1 (R=1024,C=2048, 2048 blocks/expert); else w2 (R=2048,C=1024).
__global__ void transpose_cvt_all(const float* __restrict__ w1, u16* __restrict__ w1t,
                                  const float* __restrict__ w2, u16* __restrict__ w2t) {
  __shared__ float tile[32][33];
  int bid = blockIdx.x;
  const float* wp; u16* wtp; int R, C, bx, by;
  if (bid < 16384) {
    int e = bid >> 11, t = bid & 2047;
    bx = t & 63; by = t >> 6;                 // C/32=64, R/32=32
    R = D_DIM; C = H_DIM;
    wp = w1 + (size_t)e * R * C; wtp = w1t + (size_t)e * R * C;
  } else {
    int r = bid - 16384;
    int e = r >> 11, t = r & 2047;
    bx = t & 31; by = t >> 5;                 // C/32=32, R/32=64
    R = H_DIM; C = O_DIM;
    wp = w2 + (size_t)e * R * C; wtp = w2t + (size_t)e * R * C;
  }
  int c0 = bx * 32, r0 = by * 32;
  int tx = threadIdx.x, ty = threadIdx.y;  // (32,8)
  #pragma unroll
  for (int j = 0; j < 32; j += 8)
    tile[ty + j][tx] = wp[(size_t)(r0 + ty + j) * C + c0 + tx];
  __syncthreads();
  #pragma unroll
  for (int j = 0; j < 32; j += 8)
    wtp[(size_t)(c0 + ty + j) * R + r0 + tx] = f2bf(tile[tx][ty + j]);
}

// ---------------- gating + x->bf16 cast + expert histogram (padded atomics) ----
__global__ void gate_kernel(const float* __restrict__ x, const float* __restrict__ gw,
                            const float* __restrict__ gb, int* __restrict__ topk_idx,
                            float* __restrict__ topk_val, u16* __restrict__ xb,
                            int* __restrict__ counts_pad) {
  int t = blockIdx.x * 4 + (threadIdx.x >> 6);   // one wave per token
  int lane = threadIdx.x & 63;
  const float4* xr4 = (const float4*)(x + (size_t)t * D_DIM);
  const float4* gw4 = (const float4*)gw;
  u16* xbr = xb + (size_t)t * D_DIM;
  float acc[E_NUM];
  #pragma unroll
  for (int e = 0; e < E_NUM; e++) acc[e] = 0.f;
  #pragma unroll
  for (int it = 0; it < D_DIM / 256; ++it) {
    float4 xv = xr4[it * 64 + lane];
    ushort4 o;
    o.x = f2bf(xv.x); o.y = f2bf(xv.y); o.z = f2bf(xv.z); o.w = f2bf(xv.w);
    *(ushort4*)(xbr + (it * 64 + lane) * 4) = o;
    #pragma unroll
    for (int e = 0; e < E_NUM; e++) {
      float4 wv = gw4[e * (D_DIM / 4) + it * 64 + lane];
      acc[e] += xv.x * wv.x + xv.y * wv.y + xv.z * wv.z + xv.w * wv.w;
    }
  }
  #pragma unroll
  for (int e = 0; e < E_NUM; e++) {
    #pragma unroll
    for (int o = 32; o > 0; o >>= 1) acc[e] += __shfl_down(acc[e], o);
  }
  if (lane == 0) {
    float l[E_NUM], mx = -1e30f;
    #pragma unroll
    for (int e = 0; e < E_NUM; e++) { l[e] = acc[e] + gb[e]; mx = fmaxf(mx, l[e]); }
    float p[E_NUM], s = 0.f;
    #pragma unroll
    for (int e = 0; e < E_NUM; e++) { p[e] = expf(l[e] - mx); s += p[e]; }
    float inv = 1.f / s;
    int i1 = 0;
    #pragma unroll
    for (int e = 1; e < E_NUM; e++) if (p[e] > p[i1]) i1 = e;   // strict >: lowest idx on tie
    int i2 = (i1 == 0) ? 1 : 0;
    #pragma unroll
    for (int e = 0; e < E_NUM; e++) if (e != i1 && e != i2 && p[e] > p[i2]) i2 = e;
    topk_idx[t * 2] = i1;     topk_idx[t * 2 + 1] = i2;
    topk_val[t * 2] = p[i1] * inv; topk_val[t * 2 + 1] = p[i2] * inv;
    atomicAdd(&counts_pad[i1 * 32], 1);
    atomicAdd(&counts_pad[i2 * 32], 1);
  }
}

// ---------------- scatter: local prefix from counts + padded global cursors ----
// writes pair_token and inv_pos[t*2+slot] (pair position of token t's experts)
__global__ void scatter_kernel(const int* __restrict__ topk_idx,
                               const int* __restrict__ counts_pad, int* __restrict__ cursor_pad,
                               int* __restrict__ pair_token, int* __restrict__ inv_pos) {
  __shared__ int lhist[E_NUM];
  __shared__ int lbase[E_NUM];
  int tid = threadIdx.x;
  int t = blockIdx.x * 256 + tid;
  if (tid < E_NUM) lhist[tid] = 0;
  __syncthreads();
  int e0 = topk_idx[t * 2], e1 = topk_idx[t * 2 + 1];
  int r0 = atomicAdd(&lhist[e0], 1);
  int r1 = atomicAdd(&lhist[e1], 1);
  __syncthreads();
  if (tid < E_NUM) {
    int s = 0;
    for (int ee = 0; ee < tid; ee++) s += counts_pad[ee * 32];   // eoff[tid]
    lbase[tid] = s + atomicAdd(&cursor_pad[tid * 32], lhist[tid]);
  }
  __syncthreads();
  int p0 = lbase[e0] + r0;
  int p1 = lbase[e1] + r1;
  pair_token[p0] = t;
  pair_token[p1] = t;
  inv_pos[t * 2] = p0;
  inv_pos[t * 2 + 1] = p1;
}

// ---------------- combine: out[t] = g0*obuf[p0] + g1*obuf[p1] (no atomics) ----
__global__ void combine_kernel(const float* __restrict__ obuf, const int* __restrict__ inv_pos,
                               const float* __restrict__ topk_val, float* __restrict__ out) {
  int t = blockIdx.x;
  int tid = threadIdx.x;            // 256 threads, float4 each -> 1024 floats
  int p0 = inv_pos[t * 2], p1 = inv_pos[t * 2 + 1];
  float g0 = topk_val[t * 2], g1 = topk_val[t * 2 + 1];
  const float4* a4 = (const float4*)(obuf + (size_t)p0 * O_DIM);
  const float4* b4 = (const float4*)(obuf + (size_t)p1 * O_DIM);
  float4 a = a4[tid], b = b4[tid];
  float4 r;
  r.x = g0 * a.x + g1 * b.x;
  r.y = g0 * a.y + g1 * b.y;
  r.z = g0 * a.z + g1 * b.z;
  r.w = g0 * a.w + g1 * b.w;
  ((float4*)(out + (size_t)t * O_DIM))[tid] = r;
}

// ===================== GEMM core (R5-verified, tied-best 451us config) =====================
// BK=32, TRIPLE-buffered, six distinct __shared__ arrays, static 3-phase unroll,
// counted VMCNT(8) keeps 2 tiles in flight across barriers. 48KB LDS -> 3 blocks/CU.
// LDS layout: BK=32 rows (64B) pair-packed into 64 physical 128B rows with the
// XOR-involution (0 bank conflicts, verified rounds 0-5).
// Per-block tile decode: walk counts_pad (8 scalar iters, no reg-array indexing).

#define TILE_WALK(YB, E_, M0_, NE_, OFF_)                                      \
  int E_ = 0, M0_ = -1, NE_ = 0, OFF_ = 0;                                     \
  {                                                                            \
    int nb = 0, s = 0;                                                         \
    _Pragma("unroll")                                                          \
    for (int ee = 0; ee < E_NUM; ee++) {                                       \
      int c = counts_pad[ee * 32];                                             \
      int tt = (c + 127) >> 7;                                                 \
      if (M0_ < 0 && (YB) < nb + tt) { E_ = ee; M0_ = ((YB) - nb) << 7; NE_ = c; OFF_ = s; } \
      nb += tt; s += c;                                                        \
    }                                                                          \
  }                                                                            \
  if (M0_ < 0) return

#define GEMM_DECLS                                                             \
  __shared__ __align__(16) u16 As0[4096], Bs0[4096], As1[4096], Bs1[4096],     \
      As2[4096], Bs2[4096];                                                    \
  const int tid = threadIdx.x;                                                 \
  const int wid = tid >> 6;                                                    \
  const int lane = tid & 63;                                                   \
  const int wm = (wid & 1) * 64;                                               \
  const int wn = (wid >> 1) * 64;                                              \
  const int lrow = lane & 15;                                                  \
  const int quad = lane >> 4;                                                  \
  f32x4 acc[4][4] = {};                                                        \
  auto STAGE = [&](u16* Ab, u16* Bb, int k0) {                                 \
    _Pragma("unroll")                                                          \
    for (int j = 0; j < 2; j++) {                                              \
      gload16(aptrA[j] + k0, Ab + (wid * 16 + j * 8) * 64);                    \
      gload16(bptrB[j] + k0, Bb + (wid * 16 + j * 8) * 64);                    \
    }                                                                          \
  };                                                                           \
  auto COMPUTE = [&](const u16* Ab, const u16* Bb) {                           \
    bf16x8 af[4], bfr[4];                                                      \
    _Pragma("unroll")                                                          \
    for (int i = 0; i < 4; i++) {                                              \
      int r = wm + i * 16 + lrow;                                              \
      int p = r >> 1;                                                          \
      int s = (((r & 1) << 2) | quad) ^ (p & 7);                               \
      af[i] = *(const bf16x8*)&Ab[p * 64 + s * 8];                             \
    }                                                                          \
    _Pragma("unroll")                                                          \
    for (int j = 0; j < 4; j++) {                                              \
      int r = wn + j * 16 + lrow;                                              \
      int p = r >> 1;                                                          \
      int s = (((r & 1) << 2) | quad) ^ (p & 7);                               \
      bfr[j] = *(const bf16x8*)&Bb[p * 64 + s * 8];                            \
    }                                                                          \
    __builtin_amdgcn_s_setprio(1);                                             \
    _Pragma("unroll")                                                          \
    for (int i = 0; i < 4; i++)                                                \
      _Pragma("unroll")                                                        \
      for (int j = 0; j < 4; j++)                                              \
        acc[i][j] = __builtin_amdgcn_mfma_f32_16x16x32_bf16(af[i], bfr[j],     \
                                                            acc[i][j], 0, 0, 0);\
    __builtin_amdgcn_s_setprio(0);                                             \
  }

// ---------------- GEMM1: h = relu(x[tok] @ w1[e] + b1[e]) -> hbuf bf16 ----------------
__global__ __launch_bounds__(256, 3) void gemm1_kernel(
    const u16* __restrict__ xb, const u16* __restrict__ w1t, const float* __restrict__ b1,
    const int* __restrict__ pair_token, const int* __restrict__ counts_pad,
    u16* __restrict__ hbuf) {
  // XCD-chunk swizzle over nwg = 16*GY_MAX = 2176 (chunk 272)
  int lin = blockIdx.y * 16 + blockIdx.x;
  int swz = (lin & 7) * (16 * GY_MAX / 8) + (lin >> 3);
  const int bx = swz & 15;
  const int yb = swz >> 4;
  TILE_WALK(yb, e, m0t, ne, off);
  const int n0 = bx * 128;

  // per-lane staging source addresses (inverse-swizzled), 2 issues each A,B
  const u16* aptrA[2]; const u16* bptrB[2];
  {
    const int wid_ = threadIdx.x >> 6, lane_ = threadIdx.x & 63;
    #pragma unroll
    for (int j = 0; j < 2; j++) {
      int p = wid_ * 16 + j * 8 + (lane_ >> 3);
      int u = (lane_ & 7) ^ (p & 7);
      int r = 2 * p + (u >> 2);
      int c = u & 3;
      int gm = m0t + r;
      int tok = (gm < ne) ? pair_token[off + gm] : 0;
      aptrA[j] = xb + (size_t)tok * D_DIM + c * 8;
      bptrB[j] = w1t + ((size_t)e * H_DIM + (n0 + r)) * D_DIM + c * 8;
    }
  }

  GEMM_DECLS;

  // NT = D_DIM/32 = 32 tiles
  STAGE(As0, Bs0, 0); STAGE(As1, Bs1, 32); STAGE(As2, Bs2, 64);
  #pragma unroll 1
  for (int t = 0; t <= 32 - 6; t += 3) {
    VMCNT(8); barsync(); COMPUTE(As0, Bs0); barsync(); STAGE(As0, Bs0, (t + 3) * 32);
    VMCNT(8); barsync(); COMPUTE(As1, Bs1); barsync(); STAGE(As1, Bs1, (t + 4) * 32);
    VMCNT(8); barsync(); COMPUTE(As2, Bs2); barsync(); STAGE(As2, Bs2, (t + 5) * 32);
  }
  // tail: phases 27..31 (buffers 0,1,2,0,1), stages for tiles 30,31
  VMCNT(8); barsync(); COMPUTE(As0, Bs0); barsync(); STAGE(As0, Bs0, 30 * 32);
  VMCNT(8); barsync(); COMPUTE(As1, Bs1); barsync(); STAGE(As1, Bs1, 31 * 32);
  VMCNT(8); barsync(); COMPUTE(As2, Bs2);
  VMCNT(4); barsync(); COMPUTE(As0, Bs0);
  VMCNT(0); barsync(); COMPUTE(As1, Bs1);

  // epilogue: +b1, relu, bf16 store. C/D: col=lane&15, row=quad*4+reg
  #pragma unroll
  for (int i = 0; i < 4; i++) {
    #pragma unroll
    for (int r = 0; r < 4; r++) {
      int m = wm + i * 16 + quad * 4 + r;
      int gm = m0t + m;
      if (gm >= ne) continue;
      size_t rowbase = (size_t)(off + gm) * H_DIM;
      #pragma unroll
      for (int j = 0; j < 4; j++) {
        int n = n0 + wn + j * 16 + lrow;
        float v = acc[i][j][r] + b1[e * H_DIM + n];
        v = v > 0.f ? v : 0.f;
        hbuf[rowbase + n] = f2bf(v);
      }
    }
  }
}

// ---------------- GEMM2: obuf[pair] = h[pair] @ w2[e] + b2[e] (plain stores) ----
__global__ __launch_bounds__(256, 3) void gemm2_kernel(
    const u16* __restrict__ hbuf, const u16* __restrict__ w2t, const float* __restrict__ b2,
    const int* __restrict__ counts_pad, float* __restrict__ obuf) {
  // XCD-chunk swizzle over nwg = 8*GY_MAX = 1088 (chunk 136)
  int lin = blockIdx.y * 8 + blockIdx.x;
  int swz = (lin & 7) * (8 * GY_MAX / 8) + (lin >> 3);
  const int bx = swz & 7;
  const int yb = swz >> 3;
  TILE_WALK(yb, e, m0t, ne, off);
  const int n0 = bx * 128;

  const u16* aptrA[2]; const u16* bptrB[2];
  {
    const int wid_ = threadIdx.x >> 6, lane_ = threadIdx.x & 63;
    #pragma unroll
    for (int j = 0; j < 2; j++) {
      int p = wid_ * 16 + j * 8 + (lane_ >> 3);
      int u = (lane_ & 7) ^ (p & 7);
      int r = 2 * p + (u >> 2);
      int c = u & 3;
      // hbuf has 128 slack rows past NPAIR; out-of-range rows discarded in epilogue
      aptrA[j] = hbuf + (size_t)(off + m0t + r) * H_DIM + c * 8;
      bptrB[j] = w2t + ((size_t)e * O_DIM + (n0 + r)) * H_DIM + c * 8;
    }
  }

  GEMM_DECLS;

  // NT = H_DIM/32 = 64 tiles
  STAGE(As0, Bs0, 0); STAGE(As1, Bs1, 32); STAGE(As2, Bs2, 64);
  #pragma unroll 1
  for (int t = 0; t <= 64 - 6; t += 3) {
    VMCNT(8); barsync(); COMPUTE(As0, Bs0); barsync(); STAGE(As0, Bs0, (t + 3) * 32);
    VMCNT(8); barsync(); COMPUTE(As1, Bs1); barsync(); STAGE(As1, Bs1, (t + 4) * 32);
    VMCNT(8); barsync(); COMPUTE(As2, Bs2); barsync(); STAGE(As2, Bs2, (t + 5) * 32);
  }
  // tail: phases 60..63 (buffers 0,1,2,0), stage for tile 63
  VMCNT(8); barsync(); COMPUTE(As0, Bs0); barsync(); STAGE(As0, Bs0, 63 * 32);
  VMCNT(8); barsync(); COMPUTE(As1, Bs1);
  VMCNT(4); barsync(); COMPUTE(As2, Bs2);
  VMCNT(0); barsync(); COMPUTE(As0, Bs0);

  // epilogue: +b2, plain f32 store into private pair row (NO atomics;
  // gate weighting + token reduction happen in combine_kernel)
  #pragma unroll
  for (int i = 0; i < 4; i++) {
    #pragma unroll
    for (int r = 0; r < 4; r++) {
      int m = wm + i * 16 + quad * 4 + r;
      int gm = m0t + m;
      if (gm >= ne) continue;
      size_t rowbase = (size_t)(off + gm) * O_DIM;
      #pragma unroll
      for (int j = 0; j < 4; j++) {
        int n = n0 + wn + j * 16 + lrow;
        obuf[rowbase + n] = acc[i][j][r] + b2[e * O_DIM + n];
      }
    }
  }
}

extern "C" void kernel_launch(void* const* d_in, const int* in_sizes, int n_in,
                              void* d_out, int out_size, void* d_ws, size_t ws_size,
                              hipStream_t stream) {
  const float* x  = (const float*)d_in[0];
  const float* gw = (const float*)d_in[1];
  const float* gb = (const float*)d_in[2];
  const float* w1 = (const float*)d_in[3];
  const float* b1 = (const float*)d_in[4];
  const float* w2 = (const float*)d_in[5];
  const float* b2 = (const float*)d_in[6];
  float* out = (float*)d_out;

  char* ws = (char*)d_ws;
  size_t off = 0;
  auto take = [&](size_t bytes) -> char* {
    char* p = ws + off;
    off = (off + bytes + 255) & ~(size_t)255;
    return p;
  };
  int*   meta       = (int*)take(4096);  // cursor_pad[256] | counts_pad[256]
  int*   cursor_pad = meta;
  int*   counts_pad = meta + 256;
  int*   topk_idx   = (int*)take((size_t)T_TOKENS * 2 * 4);
  float* topk_val   = (float*)take((size_t)T_TOKENS * 2 * 4);
  int*   pair_token = (int*)take((size_t)(NPAIR + 256) * 4);
  int*   inv_pos    = (int*)take((size_t)T_TOKENS * 2 * 4);
  u16*   xb         = (u16*)take((size_t)T_TOKENS * D_DIM * 2);
  u16*   w1t        = (u16*)take((size_t)E_NUM * D_DIM * H_DIM * 2);
  u16*   w2t        = (u16*)take((size_t)E_NUM * H_DIM * O_DIM * 2);
  u16*   hbuf       = (u16*)take((size_t)(NPAIR + 128) * H_DIM * 2);
  float* obuf       = (float*)take((size_t)(NPAIR + 128) * O_DIM * 4);

  hipMemsetAsync(meta, 0, 4096, stream);

  transpose_cvt_all<<<dim3(32768), dim3(32, 8), 0, stream>>>(w1, w1t, w2, w2t);
  gate_kernel<<<T_TOKENS / 4, 256, 0, stream>>>(x, gw, gb, topk_idx, topk_val, xb, counts_pad);
  scatter_kernel<<<T_TOKENS / 256, 256, 0, stream>>>(topk_idx, counts_pad, cursor_pad, pair_token, inv_pos);
  gemm1_kernel<<<dim3(16, GY_MAX), 256, 0, stream>>>(xb, w1t, b1, pair_token, counts_pad, hbuf);
  gemm2_kernel<<<dim3(8, GY_MAX), 256, 0, stream>>>(hbuf, w2t, b2, counts_pad, obuf);
  combine_kernel<<<T_TOKENS, 256, 0, stream>>>(obuf, inv_pos, topk_val, out);
}